// Round 4
// baseline (266.012 us; speedup 1.0000x reference)
//
#include <hip/hip_runtime.h>
#include <hip/hip_bf16.h>
#include <stdint.h>

// Problem constants (from reference): B=16384, F=32, D=64, H=2*D=128.
#define B_SZ 16384
#define F_SZ 32
#define D_SZ 64
#define H_SZ 128
#define RSTRIDE 72   // LDS row stride in shorts (144 B). 8 lanes per 4-bank
                     // group for ds_read_b128 = throughput-minimum (benign).

typedef __attribute__((ext_vector_type(8))) short  short8;   // 8 x bf16 MFMA frag
typedef __attribute__((ext_vector_type(4))) float  float4v;  // MFMA acc
typedef __attribute__((ext_vector_type(4))) unsigned int uint4v;

// round-half-up f32->bf16, pack (lo -> bits[15:0], hi -> bits[31:16])
__device__ __forceinline__ unsigned int pkbf(float lo, float hi) {
  unsigned int ulo = __builtin_bit_cast(unsigned int, lo) + 0x8000u;
  unsigned int uhi = __builtin_bit_cast(unsigned int, hi) + 0x8000u;
  return __builtin_amdgcn_perm(uhi, ulo, 0x07060302u);
}

// Kernel 1: W1 [F][D][H] f32 -> w1t [F][H][D] bf16 (A-fragment order), and
// pack {b1,w2} per h into one u32 (b1 hi16, w2 lo16).
__global__ __launch_bounds__(256) void ContMlp_prep(
    const float* __restrict__ W1, const float* __restrict__ b1,
    const float* __restrict__ W2, unsigned short* __restrict__ w1t,
    unsigned int* __restrict__ bw) {
  const int f  = blockIdx.x >> 2;
  const int hq = blockIdx.x & 3;
  const int h0 = hq * 32;
  const int t  = threadIdx.x;
  __shared__ float lds[D_SZ][33];
  const float* w1f = W1 + (size_t)f * (D_SZ * H_SZ);
#pragma unroll
  for (int i = 0; i < 8; ++i) {
    int idx = t + 256 * i;              // 0..2047
    int d = idx >> 5, hh = idx & 31;
    lds[d][hh] = w1f[d * H_SZ + h0 + hh];   // coalesced 128B runs
  }
  __syncthreads();
  unsigned short* o = w1t + (size_t)f * (H_SZ * D_SZ);
#pragma unroll
  for (int i = 0; i < 8; ++i) {
    int idx = t + 256 * i;
    int hh = idx >> 6, d = idx & 63;
    unsigned int u = __builtin_bit_cast(unsigned int, lds[d][hh]) + 0x8000u;
    o[(h0 + hh) * D_SZ + d] = (unsigned short)(u >> 16);
  }
  if (hq == 0 && t < H_SZ) {
    unsigned int ub = __builtin_bit_cast(unsigned int, b1[f * H_SZ + t]) + 0x8000u;
    unsigned int uw = __builtin_bit_cast(unsigned int, W2[f * H_SZ + t]) + 0x8000u;
    bw[f * H_SZ + t] = (ub & 0xFFFF0000u) | (uw >> 16);
  }
}

// Per-subtile compute: 16 batch rows x H via 8 t-tiles of mfma 16x16x32 bf16,
// K=D=64 (2 k-steps). A (weights) from LDS, B (r_) from registers. Epilogue
// folds per-t so acc liveness stays at 4 floats.
__device__ __forceinline__ void compute_sub(
    const float4v* c,
    const unsigned short* w1l, const unsigned int* bwl,
    float b2f, int col, int quad, float* store_ptr) {
  unsigned int p0 = pkbf(c[0].x, c[0].y), p1 = pkbf(c[0].z, c[0].w);
  unsigned int p2 = pkbf(c[1].x, c[1].y), p3 = pkbf(c[1].z, c[1].w);
  unsigned int p4 = pkbf(c[2].x, c[2].y), p5 = pkbf(c[2].z, c[2].w);
  unsigned int p6 = pkbf(c[3].x, c[3].y), p7 = pkbf(c[3].z, c[3].w);
  uint4v bq0 = {p0, p1, p2, p3};
  uint4v bq1 = {p4, p5, p6, p7};
  short8 bf0 = __builtin_bit_cast(short8, bq0);
  short8 bf1 = __builtin_bit_cast(short8, bq1);

  float ysum = 0.f;
#pragma unroll
  for (int t = 0; t < 8; ++t) {
    const unsigned short* wrow = w1l + (col + 16 * t) * RSTRIDE + quad * 8;
    short8 a0 = *(const short8*)(wrow);
    short8 a1 = *(const short8*)(wrow + 32);
    float4v acc = {0.f, 0.f, 0.f, 0.f};
    acc = __builtin_amdgcn_mfma_f32_16x16x32_bf16(a0, bf0, acc, 0, 0, 0);
    acc = __builtin_amdgcn_mfma_f32_16x16x32_bf16(a1, bf1, acc, 0, 0, 0);
    uint4v bwv = *(const uint4v*)(bwl + 16 * t + quad * 4);  // broadcast reads
#pragma unroll
    for (int r = 0; r < 4; ++r) {
      unsigned int u = bwv[r];
      float b1v = __builtin_bit_cast(float, u & 0xFFFF0000u);
      float w2v = __builtin_bit_cast(float, u << 16);
      ysum = fmaf(fmaxf(acc[r] + b1v, 0.f), w2v, ysum);
    }
  }
  ysum += __shfl_xor(ysum, 16, 64);
  ysum += __shfl_xor(ysum, 32, 64);
  float y = fmaxf(ysum + b2f, 0.f);
  if (quad == 0) *store_ptr = y;
}

// Kernel 2: grid = 32 row-tiles x 32 f = 1024 blocks (4/CU). Block = 4 waves,
// 512 rows; each wave runs 8 subtiles of 16 rows with a depth-2 rotating
// load pipeline (3 reg buffers). amdgpu_waves_per_eu(4,4) pins the register
// allocator's occupancy target at 4 waves/EU (128 VGPR budget) — without it
// the LDS-derived max (8 waves/EU, 64 VGPR) makes the allocator spill the
// pipeline buffers to scratch (R2/R3: 57-86 MB of scratch WRITE traffic).
__global__ __launch_bounds__(256)
__attribute__((amdgpu_waves_per_eu(4, 4)))
void ContMlp_main(
    const float* __restrict__ r_,
    const unsigned short* __restrict__ w1t, const unsigned int* __restrict__ bw,
    const float* __restrict__ b2, float* __restrict__ ydst,
    int y_fmul, int y_rmul, int y_cadd) {
  const int f    = blockIdx.x & 31;
  const int tile = blockIdx.x >> 5;            // 0..31
  const int w    = threadIdx.x >> 6;
  const int l    = threadIdx.x & 63;
  const int col  = l & 15;
  const int quad = l >> 4;

  __shared__ unsigned short w1l[H_SZ * RSTRIDE];
  __shared__ unsigned int   bwl[H_SZ];

  {  // stage 16 KB of bf16 weights, 16B chunks into padded rows
    const uint4v* src = (const uint4v*)(w1t + (size_t)f * (H_SZ * D_SZ));
#pragma unroll
    for (int i = 0; i < 4; ++i) {
      int ci = threadIdx.x + 256 * i;   // 0..1023
      int h = ci >> 3, dc = ci & 7;
      *(uint4v*)(w1l + h * RSTRIDE + dc * 8) = src[ci];
    }
    if (threadIdx.x < H_SZ) bwl[threadIdx.x] = bw[f * H_SZ + threadIdx.x];
  }
  __syncthreads();
  const float b2f = b2[f];

  const int row_w0 = tile * 512 + w * 128;     // wave's first row (8 subtiles)
  const float* rbase = r_ + (size_t)(row_w0 + col) * (F_SZ * D_SZ)
                          + f * D_SZ + quad * 8;

  float4v buf[3][4];
#define LOADSUB(S, BI)                                                      \
  do {                                                                      \
    const float* p_ = rbase + (size_t)(S) * 16 * (F_SZ * D_SZ);             \
    buf[BI][0] = *(const float4v*)(p_);                                     \
    buf[BI][1] = *(const float4v*)(p_ + 4);                                 \
    buf[BI][2] = *(const float4v*)(p_ + 32);                                \
    buf[BI][3] = *(const float4v*)(p_ + 36);                                \
  } while (0)

  LOADSUB(0, 0);
  LOADSUB(1, 1);
#pragma unroll
  for (int s = 0; s < 8; ++s) {
    if (s + 2 < 8) LOADSUB(s + 2, (s + 2) % 3);
    float* yp = ydst + (size_t)f * y_fmul
                     + (size_t)(row_w0 + s * 16 + col) * y_rmul + y_cadd;
    compute_sub(buf[s % 3], w1l, bwl, b2f, col, quad, yp);
  }
#undef LOADSUB
}

// Kernel 3 (path A): transpose-combine. Block handles 32 rows x all 32 f:
// coalesced y reads (f-major), LDS transpose, coalesced float2 writes.
__global__ __launch_bounds__(256) void ContMlp_combine(
    const float* __restrict__ X, const float* __restrict__ yws,
    float* __restrict__ out) {
  __shared__ float yl[F_SZ][33];
  const int r0 = blockIdx.x * 32;
  const int t = threadIdx.x;
#pragma unroll
  for (int i = 0; i < 4; ++i) {
    int idx = t + 256 * i;            // 0..1023
    int f = idx >> 5, r = idx & 31;
    yl[f][r] = yws[(size_t)f * B_SZ + r0 + r];
  }
  __syncthreads();
#pragma unroll
  for (int i = 0; i < 4; ++i) {
    int idx = t + 256 * i;
    int r = idx >> 5, f = idx & 31;
    float2 o2 = make_float2(X[(size_t)(r0 + r) * F_SZ + f], yl[f][r]);
    *(float2*)(out + (size_t)(r0 + r) * (2 * F_SZ) + 2 * f) = o2;
  }
}

// Kernel 3 (path B fallback): scatter X into interleaved out.
__global__ __launch_bounds__(256) void ContMlp_xwrite(
    const float* __restrict__ X, float* __restrict__ out) {
  int idx = blockIdx.x * 256 + threadIdx.x;   // 0..B*F-1
  int r = idx >> 5, f = idx & 31;
  out[(size_t)r * (2 * F_SZ) + 2 * f] = X[idx];
}

extern "C" void kernel_launch(void* const* d_in, const int* in_sizes, int n_in,
                              void* d_out, int out_size, void* d_ws, size_t ws_size,
                              hipStream_t stream) {
  const float* X  = (const float*)d_in[0];
  const float* r_ = (const float*)d_in[1];
  const float* W1 = (const float*)d_in[2];
  const float* b1 = (const float*)d_in[3];
  const float* W2 = (const float*)d_in[4];
  const float* b2 = (const float*)d_in[5];
  float* out = (float*)d_out;

  const size_t w1t_bytes = (size_t)F_SZ * H_SZ * D_SZ * 2;  // 512 KB
  const size_t bw_off    = w1t_bytes;
  const size_t bw_bytes  = (size_t)F_SZ * H_SZ * 4;         // 16 KB
  const size_t y_off     = bw_off + bw_bytes;
  const size_t y_bytes   = (size_t)B_SZ * F_SZ * 4;         // 2 MB

  unsigned short* w1t = (unsigned short*)d_ws;
  unsigned int*   bw  = (unsigned int*)((char*)d_ws + bw_off);

  ContMlp_prep<<<F_SZ * 4, 256, 0, stream>>>(W1, b1, W2, w1t, bw);

  const bool pathA = ws_size >= y_off + y_bytes;
  if (pathA) {
    float* yws = (float*)((char*)d_ws + y_off);
    ContMlp_main<<<32 * F_SZ, 256, 0, stream>>>(r_, w1t, bw, b2, yws,
                                                B_SZ, 1, 0);
    ContMlp_combine<<<B_SZ / 32, 256, 0, stream>>>(X, yws, out);
  } else {
    ContMlp_main<<<32 * F_SZ, 256, 0, stream>>>(r_, w1t, bw, b2, out,
                                                2, 2 * F_SZ, 1);
    ContMlp_xwrite<<<(B_SZ * F_SZ) / 256, 256, 0, stream>>>(X, out);
  }
}

// Round 5
// 230.287 us; speedup vs baseline: 1.1551x; 1.1551x over previous
//
#include <hip/hip_runtime.h>
#include <hip/hip_bf16.h>
#include <stdint.h>

// Problem constants (from reference): B=16384, F=32, D=64, H=2*D=128.
#define B_SZ 16384
#define F_SZ 32
#define D_SZ 64
#define H_SZ 128
#define RSTRIDE 72   // LDS row stride in shorts (144 B)

typedef __attribute__((ext_vector_type(8))) short  short8;   // 8 x bf16 MFMA frag
typedef __attribute__((ext_vector_type(4))) float  float4v;
typedef __attribute__((ext_vector_type(4))) unsigned int uint4v;

// round-half-up f32->bf16, pack (lo -> bits[15:0], hi -> bits[31:16])
__device__ __forceinline__ unsigned int pkbf(float lo, float hi) {
  unsigned int ulo = __builtin_bit_cast(unsigned int, lo) + 0x8000u;
  unsigned int uhi = __builtin_bit_cast(unsigned int, hi) + 0x8000u;
  return __builtin_amdgcn_perm(uhi, ulo, 0x07060302u);
}

// Kernel 0: stream-convert r_ f32 -> bf16 (same [B][F][D] layout). 8 floats
// per thread: 2x16B loads, 1x16B store. Spill-free by construction.
__global__ __launch_bounds__(256) void ContMlp_cvt(
    const float* __restrict__ src, unsigned int* __restrict__ dst) {
  size_t i = ((size_t)blockIdx.x * 256 + threadIdx.x) * 8;   // float index
  float4v a = *(const float4v*)(src + i);
  float4v b = *(const float4v*)(src + i + 4);
  uint4v o = {pkbf(a.x, a.y), pkbf(a.z, a.w), pkbf(b.x, b.y), pkbf(b.z, b.w)};
  *(uint4v*)(dst + i / 2) = o;
}

// Kernel 1: W1 [F][D][H] f32 -> w1t [F][H][D] bf16 (A-fragment order), and
// pack {b1,w2} per h into one u32 (b1 hi16, w2 lo16).
__global__ __launch_bounds__(256) void ContMlp_prep(
    const float* __restrict__ W1, const float* __restrict__ b1,
    const float* __restrict__ W2, unsigned short* __restrict__ w1t,
    unsigned int* __restrict__ bw) {
  const int f  = blockIdx.x >> 2;
  const int hq = blockIdx.x & 3;
  const int h0 = hq * 32;
  const int t  = threadIdx.x;
  __shared__ float lds[D_SZ][33];
  const float* w1f = W1 + (size_t)f * (D_SZ * H_SZ);
#pragma unroll
  for (int i = 0; i < 8; ++i) {
    int idx = t + 256 * i;
    int d = idx >> 5, hh = idx & 31;
    lds[d][hh] = w1f[d * H_SZ + h0 + hh];
  }
  __syncthreads();
  unsigned short* o = w1t + (size_t)f * (H_SZ * D_SZ);
#pragma unroll
  for (int i = 0; i < 8; ++i) {
    int idx = t + 256 * i;
    int hh = idx >> 6, d = idx & 63;
    unsigned int u = __builtin_bit_cast(unsigned int, lds[d][hh]) + 0x8000u;
    o[(h0 + hh) * D_SZ + d] = (unsigned short)(u >> 16);
  }
  if (hq == 0 && t < H_SZ) {
    unsigned int ub = __builtin_bit_cast(unsigned int, b1[f * H_SZ + t]) + 0x8000u;
    unsigned int uw = __builtin_bit_cast(unsigned int, W2[f * H_SZ + t]) + 0x8000u;
    bw[f * H_SZ + t] = (ub & 0xFFFF0000u) | (uw >> 16);
  }
}

// Per-subtile compute: 16 batch rows x H via 8 t-tiles of mfma 16x16x32 bf16,
// K=D=64 (2 k-steps). A (weights) from LDS, B (r_ bf16) already in regs.
__device__ __forceinline__ void compute_sub(
    short8 bf0, short8 bf1,
    const unsigned short* w1l, const unsigned int* bwl,
    float b2f, int col, int quad, float* store_ptr) {
  float ysum = 0.f;
#pragma unroll
  for (int t = 0; t < 8; ++t) {
    const unsigned short* wrow = w1l + (col + 16 * t) * RSTRIDE + quad * 8;
    short8 a0 = *(const short8*)(wrow);
    short8 a1 = *(const short8*)(wrow + 32);
    float4v acc = {0.f, 0.f, 0.f, 0.f};
    acc = __builtin_amdgcn_mfma_f32_16x16x32_bf16(a0, bf0, acc, 0, 0, 0);
    acc = __builtin_amdgcn_mfma_f32_16x16x32_bf16(a1, bf1, acc, 0, 0, 0);
    uint4v bwv = *(const uint4v*)(bwl + 16 * t + quad * 4);
#pragma unroll
    for (int r = 0; r < 4; ++r) {
      unsigned int u = bwv[r];
      float b1v = __builtin_bit_cast(float, u & 0xFFFF0000u);
      float w2v = __builtin_bit_cast(float, u << 16);
      ysum = fmaf(fmaxf(acc[r] + b1v, 0.f), w2v, ysum);
    }
  }
  ysum += __shfl_xor(ysum, 16, 64);
  ysum += __shfl_xor(ysum, 32, 64);
  float y = fmaxf(ysum + b2f, 0.f);
  if (quad == 0) *store_ptr = y;
}

// Kernel 2 (bf16 path): grid = 32 f x 32 row-tiles (f-major for L2 w1t
// residency). Block = 4 waves x 128 rows; 8 subtiles/wave. B-fragments are
// TWO 16-B global loads in exact fragment order — 8 live VGPRs, no f32
// staging, no conversion. Rolled loop + depth-1 ping-pong keeps the whole
// kernel comfortably under the 64-VGPR budget (R2-R4: f32 staging spilled).
__global__ __launch_bounds__(256) void ContMlp_main_bf(
    const unsigned short* __restrict__ rb,
    const unsigned short* __restrict__ w1t, const unsigned int* __restrict__ bw,
    const float* __restrict__ b2, float* __restrict__ ydst,
    int y_fmul, int y_rmul, int y_cadd) {
  const int f    = blockIdx.x >> 5;
  const int tile = blockIdx.x & 31;
  const int w    = threadIdx.x >> 6;
  const int l    = threadIdx.x & 63;
  const int col  = l & 15;
  const int quad = l >> 4;

  __shared__ unsigned short w1l[H_SZ * RSTRIDE];
  __shared__ unsigned int   bwl[H_SZ];
  {
    const uint4v* src = (const uint4v*)(w1t + (size_t)f * (H_SZ * D_SZ));
#pragma unroll
    for (int i = 0; i < 4; ++i) {
      int ci = threadIdx.x + 256 * i;
      int h = ci >> 3, dc = ci & 7;
      *(uint4v*)(w1l + h * RSTRIDE + dc * 8) = src[ci];
    }
    if (threadIdx.x < H_SZ) bwl[threadIdx.x] = bw[f * H_SZ + threadIdx.x];
  }
  __syncthreads();
  const float b2f = b2[f];

  const int row_w0 = tile * 512 + w * 128;
  // bf16 [B][F][D]: row stride 2048 shorts. Lane's fragment chunks at
  // d=quad*8 (frag0) and d=32+quad*8 (frag1): 16 B each.
  const unsigned short* bp = rb + (size_t)(row_w0 + col) * (F_SZ * D_SZ)
                                + f * D_SZ + quad * 8;

  short8 c0 = *(const short8*)(bp);
  short8 c1 = *(const short8*)(bp + 32);
#pragma unroll 1
  for (int s = 0; s < 8; ++s) {
    short8 n0, n1;
    if (s < 7) {
      const unsigned short* np = bp + (size_t)(s + 1) * 16 * (F_SZ * D_SZ);
      n0 = *(const short8*)(np);
      n1 = *(const short8*)(np + 32);
    }
    float* yp = ydst + (size_t)f * y_fmul
                     + (size_t)(row_w0 + s * 16 + col) * y_rmul + y_cadd;
    compute_sub(c0, c1, w1l, bwl, b2f, col, quad, yp);
    c0 = n0; c1 = n1;
  }
}

// Kernel 2 (f32 fallback if ws can't hold the bf16 copy of r_).
__global__ __launch_bounds__(256) void ContMlp_main_f32(
    const float* __restrict__ r_,
    const unsigned short* __restrict__ w1t, const unsigned int* __restrict__ bw,
    const float* __restrict__ b2, float* __restrict__ ydst,
    int y_fmul, int y_rmul, int y_cadd) {
  const int f    = blockIdx.x >> 5;
  const int tile = blockIdx.x & 31;
  const int w    = threadIdx.x >> 6;
  const int l    = threadIdx.x & 63;
  const int col  = l & 15;
  const int quad = l >> 4;

  __shared__ unsigned short w1l[H_SZ * RSTRIDE];
  __shared__ unsigned int   bwl[H_SZ];
  {
    const uint4v* src = (const uint4v*)(w1t + (size_t)f * (H_SZ * D_SZ));
#pragma unroll
    for (int i = 0; i < 4; ++i) {
      int ci = threadIdx.x + 256 * i;
      int h = ci >> 3, dc = ci & 7;
      *(uint4v*)(w1l + h * RSTRIDE + dc * 8) = src[ci];
    }
    if (threadIdx.x < H_SZ) bwl[threadIdx.x] = bw[f * H_SZ + threadIdx.x];
  }
  __syncthreads();
  const float b2f = b2[f];

  const int row_w0 = tile * 512 + w * 128;
  const float* rbase = r_ + (size_t)(row_w0 + col) * (F_SZ * D_SZ)
                          + f * D_SZ + quad * 8;
#pragma unroll 1
  for (int s = 0; s < 8; ++s) {
    const float* p_ = rbase + (size_t)s * 16 * (F_SZ * D_SZ);
    float4v r0 = *(const float4v*)(p_);
    float4v r1 = *(const float4v*)(p_ + 4);
    float4v r2 = *(const float4v*)(p_ + 32);
    float4v r3 = *(const float4v*)(p_ + 36);
    uint4v bq0 = {pkbf(r0.x, r0.y), pkbf(r0.z, r0.w), pkbf(r1.x, r1.y), pkbf(r1.z, r1.w)};
    uint4v bq1 = {pkbf(r2.x, r2.y), pkbf(r2.z, r2.w), pkbf(r3.x, r3.y), pkbf(r3.z, r3.w)};
    float* yp = ydst + (size_t)f * y_fmul
                     + (size_t)(row_w0 + s * 16 + col) * y_rmul + y_cadd;
    compute_sub(__builtin_bit_cast(short8, bq0), __builtin_bit_cast(short8, bq1),
                w1l, bwl, b2f, col, quad, yp);
  }
}

// Kernel 3: transpose-combine. 32 rows x 32 f per block: coalesced y reads
// (f-major ws), LDS transpose, coalesced float2 writes of (X, y).
__global__ __launch_bounds__(256) void ContMlp_combine(
    const float* __restrict__ X, const float* __restrict__ yws,
    float* __restrict__ out) {
  __shared__ float yl[F_SZ][33];
  const int r0 = blockIdx.x * 32;
  const int t = threadIdx.x;
#pragma unroll
  for (int i = 0; i < 4; ++i) {
    int idx = t + 256 * i;
    int f = idx >> 5, r = idx & 31;
    yl[f][r] = yws[(size_t)f * B_SZ + r0 + r];
  }
  __syncthreads();
#pragma unroll
  for (int i = 0; i < 4; ++i) {
    int idx = t + 256 * i;
    int r = idx >> 5, f = idx & 31;
    float2 o2 = make_float2(X[(size_t)(r0 + r) * F_SZ + f], yl[f][r]);
    *(float2*)(out + (size_t)(r0 + r) * (2 * F_SZ) + 2 * f) = o2;
  }
}

// Fallback X-scatter for the no-workspace path.
__global__ __launch_bounds__(256) void ContMlp_xwrite(
    const float* __restrict__ X, float* __restrict__ out) {
  int idx = blockIdx.x * 256 + threadIdx.x;
  int r = idx >> 5, f = idx & 31;
  out[(size_t)r * (2 * F_SZ) + 2 * f] = X[idx];
}

extern "C" void kernel_launch(void* const* d_in, const int* in_sizes, int n_in,
                              void* d_out, int out_size, void* d_ws, size_t ws_size,
                              hipStream_t stream) {
  const float* X  = (const float*)d_in[0];
  const float* r_ = (const float*)d_in[1];
  const float* W1 = (const float*)d_in[2];
  const float* b1 = (const float*)d_in[3];
  const float* W2 = (const float*)d_in[4];
  const float* b2 = (const float*)d_in[5];
  float* out = (float*)d_out;

  const size_t w1t_bytes = (size_t)F_SZ * H_SZ * D_SZ * 2;   // 512 KB
  const size_t bw_off    = w1t_bytes;
  const size_t bw_bytes  = (size_t)F_SZ * H_SZ * 4;          // 16 KB
  const size_t y_off     = bw_off + bw_bytes;
  const size_t y_bytes   = (size_t)B_SZ * F_SZ * 4;          // 2 MB
  const size_t rb_off    = (y_off + y_bytes + 255) & ~(size_t)255;
  const size_t rb_bytes  = (size_t)B_SZ * F_SZ * D_SZ * 2;   // 64 MB

  unsigned short* w1t = (unsigned short*)d_ws;
  unsigned int*   bw  = (unsigned int*)((char*)d_ws + bw_off);

  ContMlp_prep<<<F_SZ * 4, 256, 0, stream>>>(W1, b1, W2, w1t, bw);

  const bool haveY  = ws_size >= y_off + y_bytes;
  const bool haveRb = ws_size >= rb_off + rb_bytes;

  if (haveRb) {
    unsigned short* rb = (unsigned short*)((char*)d_ws + rb_off);
    float* yws = (float*)((char*)d_ws + y_off);
    const size_t nElem = (size_t)B_SZ * F_SZ * D_SZ;          // 32M floats
    ContMlp_cvt<<<(unsigned)(nElem / (256 * 8)), 256, 0, stream>>>(r_, (unsigned int*)rb);
    ContMlp_main_bf<<<32 * F_SZ, 256, 0, stream>>>(rb, w1t, bw, b2, yws,
                                                   B_SZ, 1, 0);
    ContMlp_combine<<<B_SZ / 32, 256, 0, stream>>>(X, yws, out);
  } else if (haveY) {
    float* yws = (float*)((char*)d_ws + y_off);
    ContMlp_main_f32<<<32 * F_SZ, 256, 0, stream>>>(r_, w1t, bw, b2, yws,
                                                    B_SZ, 1, 0);
    ContMlp_combine<<<B_SZ / 32, 256, 0, stream>>>(X, yws, out);
  } else {
    ContMlp_main_f32<<<32 * F_SZ, 256, 0, stream>>>(r_, w1t, bw, b2, out,
                                                    2, 2 * F_SZ, 1);
    ContMlp_xwrite<<<(B_SZ * F_SZ) / 256, 256, 0, stream>>>(X, out);
  }
}

// Round 6
// 213.241 us; speedup vs baseline: 1.2475x; 1.0799x over previous
//
#include <hip/hip_runtime.h>
#include <stdint.h>

// Problem constants (from reference): B=16384, F=32, D=64, H=2*D=128.
#define B_SZ 16384
#define F_SZ 32
#define D_SZ 64
#define H_SZ 128
#define RSTRIDE 72   // w1l LDS row stride in shorts (144 B) -> conflict-free A-frag reads

typedef __attribute__((ext_vector_type(8))) short  short8;   // 8 x bf16 MFMA frag
typedef __attribute__((ext_vector_type(4))) float  float4v;
typedef __attribute__((ext_vector_type(4))) unsigned int uint4v;

// round-half-up f32->bf16, pack (lo -> bits[15:0], hi -> bits[31:16])
__device__ __forceinline__ unsigned int pkbf(float lo, float hi) {
  unsigned int ulo = __builtin_bit_cast(unsigned int, lo) + 0x8000u;
  unsigned int uhi = __builtin_bit_cast(unsigned int, hi) + 0x8000u;
  return __builtin_amdgcn_perm(uhi, ulo, 0x07060302u);
}

// Kernel 1: W1 [F][D][H] f32 -> w1t [F][H][D] bf16 (A-fragment order), and
// pack {b1,w2} per h into one u32 (b1 hi16, w2 lo16).
__global__ __launch_bounds__(256) void ContMlp_prep(
    const float* __restrict__ W1, const float* __restrict__ b1,
    const float* __restrict__ W2, unsigned short* __restrict__ w1t,
    unsigned int* __restrict__ bw) {
  const int f  = blockIdx.x >> 2;
  const int hq = blockIdx.x & 3;
  const int h0 = hq * 32;
  const int t  = threadIdx.x;
  __shared__ float lds[D_SZ][33];
  const float* w1f = W1 + (size_t)f * (D_SZ * H_SZ);
#pragma unroll
  for (int i = 0; i < 8; ++i) {
    int idx = t + 256 * i;
    int d = idx >> 5, hh = idx & 31;
    lds[d][hh] = w1f[d * H_SZ + h0 + hh];
  }
  __syncthreads();
  unsigned short* o = w1t + (size_t)f * (H_SZ * D_SZ);
#pragma unroll
  for (int i = 0; i < 8; ++i) {
    int idx = t + 256 * i;
    int hh = idx >> 6, d = idx & 63;
    unsigned int u = __builtin_bit_cast(unsigned int, lds[d][hh]) + 0x8000u;
    o[(h0 + hh) * D_SZ + d] = (unsigned short)(u >> 16);
  }
  if (hq == 0 && t < H_SZ) {
    unsigned int ub = __builtin_bit_cast(unsigned int, b1[f * H_SZ + t]) + 0x8000u;
    unsigned int uw = __builtin_bit_cast(unsigned int, W2[f * H_SZ + t]) + 0x8000u;
    bw[f * H_SZ + t] = (ub & 0xFFFF0000u) | (uw >> 16);
  }
}

// Kernel 2: single-pass f32 main. Grid = 32 row-tiles x 32 f = 1024 blocks.
// Block = 4 waves x 128 rows; 8 subtiles of 16 rows per wave.
//
// r_ staging: __builtin_amdgcn_global_load_lds width=16 into a per-wave 4 KB
// LDS buffer — ZERO staging VGPRs (R2-R5: f32 staging in VGPRs spilled at the
// LDS-implied 64-VGPR budget). Chunk-major slot layout (slot = c*16 + r,
// 16B slots; instr i lane l -> c = i*4+quad, r = col) so that:
//   * global addrs per instr: per row one contiguous 64B line (good segments)
//   * fragment ds_read_b128 at (c*16+col)*16 -> bank group col*4 mod 32:
//     conflict-free.
// Loop VMEM = exactly the 4 global_load_lds per subtile; y kept in registers
// and stored after the loop, so s_waitcnt vmcnt(0) waits only on staging.
// LDS total ~35 KB -> 4 blocks/CU (raises compiler VGPR budget to 128).
__global__ __launch_bounds__(256) void ContMlp_main(
    const float* __restrict__ r_,
    const unsigned short* __restrict__ w1t, const unsigned int* __restrict__ bw,
    const float* __restrict__ b2, float* __restrict__ ydst,
    int y_fmul, int y_rmul, int y_cadd) {
  const int f    = blockIdx.x & 31;
  const int tile = blockIdx.x >> 5;
  const int w    = threadIdx.x >> 6;
  const int l    = threadIdx.x & 63;
  const int col  = l & 15;
  const int quad = l >> 4;

  __shared__ unsigned short w1l[H_SZ * RSTRIDE];   // 18432 B
  __shared__ unsigned int   bwl[H_SZ];             // 512 B
  __shared__ float          rbuf[4][1024];         // 16384 B, 4 KB per wave

  {  // stage weights (once per block)
    const uint4v* src = (const uint4v*)(w1t + (size_t)f * (H_SZ * D_SZ));
#pragma unroll
    for (int i = 0; i < 4; ++i) {
      int ci = threadIdx.x + 256 * i;
      int h = ci >> 3, dc = ci & 7;
      *(uint4v*)(w1l + h * RSTRIDE + dc * 8) = src[ci];
    }
    if (threadIdx.x < H_SZ) bwl[threadIdx.x] = bw[f * H_SZ + threadIdx.x];
  }
  __syncthreads();
  const float b2f = b2[f];

  const int row_w0 = tile * 512 + w * 128;
  // lane's staging gather base: row (row_w0 + col), float offset quad*4
  const float* gl = r_ + (size_t)(row_w0 + col) * (F_SZ * D_SZ)
                       + f * D_SZ + quad * 4;
  float* rb = &rbuf[w][0];
  float yv[8];

#pragma unroll 1
  for (int s = 0; s < 8; ++s) {
    const float* gs = gl + (size_t)s * 16 * (F_SZ * D_SZ);
#pragma unroll
    for (int i = 0; i < 4; ++i) {
      __builtin_amdgcn_global_load_lds(
          (const __attribute__((address_space(1))) void*)(gs + i * 16),
          (__attribute__((address_space(3))) void*)(rb + i * 256),
          16, 0, 0);
    }
    __builtin_amdgcn_s_waitcnt(0x0F70);   // vmcnt(0), lgkm/exp untouched

    // fragment read (chunk-major): chunk c lives at floats (c*16+col)*4
    float4v f0 = *(const float4v*)(rb + (quad * 2) * 64 + col * 4);
    float4v f1 = *(const float4v*)(rb + (quad * 2 + 1) * 64 + col * 4);
    float4v f2 = *(const float4v*)(rb + (8 + quad * 2) * 64 + col * 4);
    float4v f3 = *(const float4v*)(rb + (9 + quad * 2) * 64 + col * 4);
    uint4v bq0 = {pkbf(f0.x, f0.y), pkbf(f0.z, f0.w),
                  pkbf(f1.x, f1.y), pkbf(f1.z, f1.w)};
    uint4v bq1 = {pkbf(f2.x, f2.y), pkbf(f2.z, f2.w),
                  pkbf(f3.x, f3.y), pkbf(f3.z, f3.w)};
    short8 bf0 = __builtin_bit_cast(short8, bq0);
    short8 bf1 = __builtin_bit_cast(short8, bq1);

    float ysum = 0.f;
#pragma unroll
    for (int t = 0; t < 8; ++t) {
      const unsigned short* wrow = w1l + (col + 16 * t) * RSTRIDE + quad * 8;
      short8 a0 = *(const short8*)(wrow);
      short8 a1 = *(const short8*)(wrow + 32);
      float4v acc = {0.f, 0.f, 0.f, 0.f};
      acc = __builtin_amdgcn_mfma_f32_16x16x32_bf16(a0, bf0, acc, 0, 0, 0);
      acc = __builtin_amdgcn_mfma_f32_16x16x32_bf16(a1, bf1, acc, 0, 0, 0);
      uint4v bwv = *(const uint4v*)(bwl + 16 * t + quad * 4);
#pragma unroll
      for (int r = 0; r < 4; ++r) {
        unsigned int u = bwv[r];
        float b1v = __builtin_bit_cast(float, u & 0xFFFF0000u);
        float w2v = __builtin_bit_cast(float, u << 16);
        ysum = fmaf(fmaxf(acc[r] + b1v, 0.f), w2v, ysum);
      }
    }
    ysum += __shfl_xor(ysum, 16, 64);
    ysum += __shfl_xor(ysum, 32, 64);
    yv[s] = fmaxf(ysum + b2f, 0.f);
  }

  if (quad == 0) {
#pragma unroll
    for (int s = 0; s < 8; ++s) {
      float* yp = ydst + (size_t)f * y_fmul
                       + (size_t)(row_w0 + s * 16 + col) * y_rmul + y_cadd;
      *yp = yv[s];
    }
  }
}

// Kernel 3: transpose-combine. 32 rows x 32 f per block: coalesced y reads
// (f-major ws), LDS transpose, coalesced float2 writes of (X, y).
__global__ __launch_bounds__(256) void ContMlp_combine(
    const float* __restrict__ X, const float* __restrict__ yws,
    float* __restrict__ out) {
  __shared__ float yl[F_SZ][33];
  const int r0 = blockIdx.x * 32;
  const int t = threadIdx.x;
#pragma unroll
  for (int i = 0; i < 4; ++i) {
    int idx = t + 256 * i;
    int f = idx >> 5, r = idx & 31;
    yl[f][r] = yws[(size_t)f * B_SZ + r0 + r];
  }
  __syncthreads();
#pragma unroll
  for (int i = 0; i < 4; ++i) {
    int idx = t + 256 * i;
    int r = idx >> 5, f = idx & 31;
    float2 o2 = make_float2(X[(size_t)(r0 + r) * F_SZ + f], yl[f][r]);
    *(float2*)(out + (size_t)(r0 + r) * (2 * F_SZ) + 2 * f) = o2;
  }
}

// Fallback X-scatter for the no-workspace path.
__global__ __launch_bounds__(256) void ContMlp_xwrite(
    const float* __restrict__ X, float* __restrict__ out) {
  int idx = blockIdx.x * 256 + threadIdx.x;
  int r = idx >> 5, f = idx & 31;
  out[(size_t)r * (2 * F_SZ) + 2 * f] = X[idx];
}

extern "C" void kernel_launch(void* const* d_in, const int* in_sizes, int n_in,
                              void* d_out, int out_size, void* d_ws, size_t ws_size,
                              hipStream_t stream) {
  const float* X  = (const float*)d_in[0];
  const float* r_ = (const float*)d_in[1];
  const float* W1 = (const float*)d_in[2];
  const float* b1 = (const float*)d_in[3];
  const float* W2 = (const float*)d_in[4];
  const float* b2 = (const float*)d_in[5];
  float* out = (float*)d_out;

  const size_t w1t_bytes = (size_t)F_SZ * H_SZ * D_SZ * 2;   // 512 KB
  const size_t bw_off    = w1t_bytes;
  const size_t bw_bytes  = (size_t)F_SZ * H_SZ * 4;          // 16 KB
  const size_t y_off     = bw_off + bw_bytes;
  const size_t y_bytes   = (size_t)B_SZ * F_SZ * 4;          // 2 MB

  unsigned short* w1t = (unsigned short*)d_ws;
  unsigned int*   bw  = (unsigned int*)((char*)d_ws + bw_off);

  ContMlp_prep<<<F_SZ * 4, 256, 0, stream>>>(W1, b1, W2, w1t, bw);

  if (ws_size >= y_off + y_bytes) {
    float* yws = (float*)((char*)d_ws + y_off);
    ContMlp_main<<<32 * F_SZ, 256, 0, stream>>>(r_, w1t, bw, b2, yws,
                                                B_SZ, 1, 0);
    ContMlp_combine<<<B_SZ / 32, 256, 0, stream>>>(X, yws, out);
  } else {
    ContMlp_main<<<32 * F_SZ, 256, 0, stream>>>(r_, w1t, bw, b2, out,
                                                2, 2 * F_SZ, 1);
    ContMlp_xwrite<<<(B_SZ * F_SZ) / 256, 256, 0, stream>>>(X, out);
  }
}